// Round 4
// baseline (499.736 us; speedup 1.0000x reference)
//
#include <hip/hip_runtime.h>
#include <stdint.h>

// CSSA: B=32, H=W=64, C=64, heads=4, hd=16, strip windows 64x8 -> 256 windows.
// Round 4: block = (window, q-half), 1024 thr = 16 waves; wave = (head, 64 q).
// LDS holds only V^T (all 4 heads); K streamed from global inside the K-loop
// (QK A-frag == the streamed load, no LDS); Q register-resident. 2 blocks/CU,
// target 8 waves/SIMD (VGPR<=64). Full 256B output lines per block.
#define VSTR 520    // Vt row: 512 tok + 8 pad (1040 B): frag reads conflict-free

typedef __attribute__((ext_vector_type(4))) short          short4v;
typedef __attribute__((ext_vector_type(4))) float          f32x4;

__device__ __forceinline__ unsigned short f2bf(float f) {   // round-half-up
    union { float f; unsigned int u; } x; x.f = f;
    return (unsigned short)((x.u + 0x8000u) >> 16);
}
__device__ __forceinline__ float bf2f(unsigned short u) {
    union { unsigned int i; float f; } x; x.i = ((unsigned int)u) << 16; return x.f;
}
// pack two f32 -> bf16x2 (lo,hi), round-half-up: 3 VALU
__device__ __forceinline__ unsigned int pk2bf(float lo, float hi) {
    union { float f; unsigned int u; } a, b; a.f = lo; b.f = hi;
    return __builtin_amdgcn_perm(b.u + 0x8000u, a.u + 0x8000u, 0x07060302u);
}
__device__ __forceinline__ short4v pk4bf(float a, float b, float c, float d) {
    union { short4v s; unsigned int u[2]; } p;
    p.u[0] = pk2bf(a, b);
    p.u[1] = pk2bf(c, d);
    return p.s;
}

__global__ __launch_bounds__(1024, 8)
void CSSA_69355131896243_kernel(const float* __restrict__ qkv,
                                const float* __restrict__ wconv,
                                const float* __restrict__ bconv,
                                float* __restrict__ out)
{
    __shared__ unsigned short Vt[64 * VSTR];   // 66560 B: V^T[ch][token] bf16
    __shared__ float Wl[576];                  // 64 ch x 9 conv weights
    __shared__ float Bl[64];

    const int tid  = threadIdx.x;
    const int wave = tid >> 6, lane = tid & 63, quad = lane >> 4, l15 = lane & 15;

    // bid -> (window, q-half); qh-siblings are 8 apart -> same XCD under both
    // round-robin (%8) and chunked dispatch -> V lines shared in L2.
    const int bid  = blockIdx.x;
    const int rest = bid >> 3;
    const int qh   = rest & 1;
    const int win  = (bid & 7) * 32 + (rest >> 1);
    const int b    = win >> 3, wx = win & 7;

    const size_t ONE  = (size_t)32 * 4096 * 64;
    const size_t base = ((size_t)b * 4096 + (size_t)wx * 8) * 64;
    const float* gQ = qkv + base;
    const float* gK = qkv + ONE + base;
    const float* gV = qkv + 2 * ONE + base;

    // ---- stage V^T (all 64 ch) as bf16; fully coalesced f32x4 loads ----
    {
        const int tb = tid >> 4;          // token within 64-group
        const int c4 = (tid & 15) * 4;    // 4-ch group
        #pragma unroll
        for (int r = 0; r < 8; ++r) {
            const int t = r * 64 + tb;
            f32x4 vd = *(const f32x4*)(gV + (size_t)(t >> 3) * 4096 + (size_t)(t & 7) * 64 + c4);
            #pragma unroll
            for (int j = 0; j < 4; ++j) Vt[(c4 + j) * VSTR + t] = f2bf(vd[j]);
        }
    }
    if (tid < 576) Wl[tid] = wconv[tid];
    if (tid < 64)  Bl[tid] = bconv[tid];

    // wave -> (head, 64-query range)
    const int h  = wave >> 2;
    const int q0 = qh * 256 + (wave & 3) * 64;
    const int hc = h * 16;

    // ---- Q prefetch (global, independent of LDS -> overlaps barrier) ----
    const float SCL = 0.25f * 1.44269504088896341f;   // scale * log2(e) folded into Q
    f32x4 qv[4];
    #pragma unroll
    for (int t = 0; t < 4; ++t) {
        const int q = q0 + t * 16 + l15;
        qv[t] = *(const f32x4*)(gQ + (size_t)(q >> 3) * 4096 + (size_t)(q & 7) * 64 + hc + quad * 4);
    }
    __syncthreads();

    short4v qf[4];   // B[k=d=quad*4+i][n=q=l15]
    #pragma unroll
    for (int t = 0; t < 4; ++t)
        qf[t] = pk4bf(qv[t][0] * SCL, qv[t][1] * SCL, qv[t][2] * SCL, qv[t][3] * SCL);

    f32x4 acc[4];
    float lp[4];
    #pragma unroll
    for (int t = 0; t < 4; ++t) { acc[t] = (f32x4)0.0f; lp[t] = 0.0f; }

    // ---- main loop: 32 chunks x 16 keys; K streamed from global (prefetch d1) ----
    // K A-frag: A[m=key=l15][k=d=quad*4+i] == direct f32x4 load of token c*16+l15.
    const float* gKh = gK + hc + quad * 4;
    const int kt0 = l15;
    f32x4 kv = *(const f32x4*)(gKh + (size_t)(kt0 >> 3) * 4096 + (size_t)(kt0 & 7) * 64);
    #pragma unroll 4
    for (int c = 0; c < 32; ++c) {
        f32x4 kvn;
        if (c < 31) {
            const int t = (c + 1) * 16 + l15;
            kvn = *(const f32x4*)(gKh + (size_t)(t >> 3) * 4096 + (size_t)(t & 7) * 64);
        }
        const short4v kf = pk4bf(kv[0], kv[1], kv[2], kv[3]);
        const short4v vf = *(const short4v*)(&Vt[(hc + l15) * VSTR + c * 16 + quad * 4]);
        #pragma unroll
        for (int t = 0; t < 4; ++t) {
            // s^T[key][q]; C row=quad*4+j -> key, col=l15 -> q
            f32x4 s = __builtin_amdgcn_mfma_f32_16x16x16bf16_1k(kf, qf[t], (f32x4)0.0f, 0, 0, 0);
            const float p0 = __builtin_amdgcn_exp2f(s[0]);
            const float p1 = __builtin_amdgcn_exp2f(s[1]);
            const float p2 = __builtin_amdgcn_exp2f(s[2]);
            const float p3 = __builtin_amdgcn_exp2f(s[3]);
            lp[t] += (p0 + p1) + (p2 + p3);
            // P C-layout == K=16 B-frag layout -> PV straight from registers
            acc[t] = __builtin_amdgcn_mfma_f32_16x16x16bf16_1k(vf, pk4bf(p0, p1, p2, p3), acc[t], 0, 0, 0);
        }
        kv = kvn;
    }

    // ---- denominators: cross-quad reduce ----
    float linv[4];
    #pragma unroll
    for (int t = 0; t < 4; ++t) {
        float v = lp[t];
        v += __shfl_xor(v, 16, 64);
        v += __shfl_xor(v, 32, 64);
        linv[t] = __builtin_amdgcn_rcpf(v);
    }

    // ---- epilogue: LePE from resident V^T, normalize, f32x4 full-line stores ----
    #pragma unroll
    for (int j = 0; j < 4; ++j) {
        const int d = quad * 4 + j;
        const int ch = hc + d;
        float w9[9];
        #pragma unroll
        for (int o = 0; o < 9; ++o) w9[o] = Wl[ch * 9 + o];
        const float bs = Bl[ch];
        #pragma unroll
        for (int t = 0; t < 4; ++t) {
            const int q = q0 + t * 16 + l15;
            const int y = q >> 3, x = q & 7;
            float lep = bs;
            #pragma unroll
            for (int dy = 0; dy < 3; ++dy) {
                #pragma unroll
                for (int dx = 0; dx < 3; ++dx) {
                    const int yy = y + dy - 1, xx = x + dx - 1;
                    const bool ok = ((unsigned)yy < 64u) && ((unsigned)xx < 8u);
                    const int tt = (q + (dy - 1) * 8 + (dx - 1)) & 511;   // masked if OOB
                    lep += (ok ? w9[dy * 3 + dx] : 0.0f) * bf2f(Vt[ch * VSTR + tt]);
                }
            }
            acc[t][j] = acc[t][j] * linv[t] + lep;
        }
    }
    float* gO = out + base;
    #pragma unroll
    for (int t = 0; t < 4; ++t) {
        const int q = q0 + t * 16 + l15;
        *(f32x4*)(gO + (size_t)(q >> 3) * 4096 + (size_t)(q & 7) * 64 + hc + quad * 4) = acc[t];
    }
}

extern "C" void kernel_launch(void* const* d_in, const int* in_sizes, int n_in,
                              void* d_out, int out_size, void* d_ws, size_t ws_size,
                              hipStream_t stream) {
    const float* qkv   = (const float*)d_in[0];
    const float* wconv = (const float*)d_in[1];
    const float* bconv = (const float*)d_in[2];
    float* outp = (float*)d_out;
    hipLaunchKernelGGL(CSSA_69355131896243_kernel, dim3(512), dim3(1024), 0, stream,
                       qkv, wconv, bconv, outp);
}

// Round 5
// 269.211 us; speedup vs baseline: 1.8563x; 1.8563x over previous
//
#include <hip/hip_runtime.h>
#include <stdint.h>

// CSSA: B=32, H=W=64, C=64, heads=4, hd=16, strip windows 64x8 -> 256 windows.
// Round 5: block=(window,head), 512 thr = 8 waves, wave = 64 queries (4 tiles).
// LDS = V^T only (17.3 KB). K streamed from global (QK A-frag == the f32x4 load).
// 8 waves/SIMD TLP hides latency; per-wave live state ~55 VGPR -> no spill.
#define VSTR 520    // Vt row: 512 tok + 8 pad

typedef __attribute__((ext_vector_type(4))) short short4v;
typedef __attribute__((ext_vector_type(4))) float f32x4;
typedef __bf16 bf2_t __attribute__((ext_vector_type(2)));

__device__ __forceinline__ unsigned short f2bf(float f) {   // round-half-up
    union { float f; unsigned int u; } x; x.f = f;
    return (unsigned short)((x.u + 0x8000u) >> 16);
}
__device__ __forceinline__ float bf2f(unsigned short u) {
    union { unsigned int i; float f; } x; x.i = ((unsigned int)u) << 16; return x.f;
}
__device__ __forceinline__ unsigned int pk2bf(float lo, float hi) {
#if __has_builtin(__builtin_amdgcn_cvt_pk_bf16_f32)
    union { bf2_t v; unsigned int u; } c;
    c.v = __builtin_amdgcn_cvt_pk_bf16_f32(lo, hi);     // 1 VALU op (gfx950)
    return c.u;
#else
    union { float f; unsigned int u; } a, b; a.f = lo; b.f = hi;
    return __builtin_amdgcn_perm(b.u + 0x8000u, a.u + 0x8000u, 0x07060302u);
#endif
}
__device__ __forceinline__ short4v pk4bf(float a, float b, float c, float d) {
    union { short4v s; unsigned int u[2]; } p;
    p.u[0] = pk2bf(a, b);
    p.u[1] = pk2bf(c, d);
    return p.s;
}

__global__ __launch_bounds__(512, 8)
void CSSA_69355131896243_kernel(const float* __restrict__ qkv,
                                const float* __restrict__ wconv,
                                const float* __restrict__ bconv,
                                float* __restrict__ out)
{
    __shared__ unsigned short Vt[16 * VSTR];   // 16640 B: this head's V^T[d][token]
    __shared__ float Wl[144];                  // 16 ch x 9 conv weights
    __shared__ float Bl[16];

    const int tid  = threadIdx.x;
    const int wave = tid >> 6, lane = tid & 63, quad = lane >> 4, l15 = lane & 15;

    // bid -> (window, head): 4 head-siblings of a window are 8 apart -> same XCD
    // under round-robin (%8) and adjacent under chunked dispatch -> K/V/Q/out
    // lines shared in L2 (each block touches only its head's 64B of each 256B line).
    const int bid = blockIdx.x;
    const int win = (bid & 7) * 32 + (bid >> 5);
    const int h   = (bid >> 3) & 3;
    const int b   = win >> 3, wx = win & 7;

    const size_t ONE  = (size_t)32 * 4096 * 64;
    const size_t base = ((size_t)b * 4096 + (size_t)wx * 8) * 64;
    const float* gQ = qkv + base;
    const float* gK = qkv + ONE + base;
    const float* gV = qkv + 2 * ONE + base;
    const int hc = h * 16;

    // ---- stage this head's V^T as bf16 ----
    {
        const int c4 = tid & 3;          // 4-ch group within head
        const int t0 = tid >> 2;         // 128 tokens per round
        #pragma unroll
        for (int r = 0; r < 4; ++r) {
            const int t = r * 128 + t0;
            f32x4 vd = *(const f32x4*)(gV + (size_t)(t >> 3) * 4096 + (size_t)(t & 7) * 64 + hc + c4 * 4);
            #pragma unroll
            for (int j = 0; j < 4; ++j) Vt[(c4 * 4 + j) * VSTR + t] = f2bf(vd[j]);
        }
    }
    if (tid < 144) Wl[tid] = wconv[h * 144 + tid];
    if (tid < 16)  Bl[tid] = bconv[hc + tid];

    // ---- Q prefetch + pack (independent of LDS -> overlaps barrier) ----
    const float SCL = 0.25f * 1.44269504088896341f;   // scale*log2(e) folded into Q
    const int q0 = wave * 64;
    short4v qf[4];   // B[k=d=quad*4+i][n=q=l15]
    #pragma unroll
    for (int t = 0; t < 4; ++t) {
        const int q = q0 + t * 16 + l15;
        f32x4 qv = *(const f32x4*)(gQ + (size_t)(q >> 3) * 4096 + (size_t)(q & 7) * 64 + hc + quad * 4);
        qf[t] = pk4bf(qv[0] * SCL, qv[1] * SCL, qv[2] * SCL, qv[3] * SCL);
    }
    __syncthreads();

    f32x4 acc[4];
    float lp[4];
    #pragma unroll
    for (int t = 0; t < 4; ++t) { acc[t] = (f32x4)0.0f; lp[t] = 0.0f; }

    // ---- main loop: 32 chunks x 16 keys; K streamed from global ----
    // K A-frag: A[m=key=l15][k=d=quad*4+i] == direct f32x4 load of token c*16+l15.
    const float* gKh = gK + hc + quad * 4;
    for (int c = 0; c < 32; ++c) {
        const int t = c * 16 + l15;
        f32x4 kv = *(const f32x4*)(gKh + (size_t)(t >> 3) * 4096 + (size_t)(t & 7) * 64);
        const short4v vf = *(const short4v*)(&Vt[l15 * VSTR + c * 16 + quad * 4]);
        const short4v kf = pk4bf(kv[0], kv[1], kv[2], kv[3]);
        #pragma unroll
        for (int tt = 0; tt < 4; ++tt) {
            // s^T[key][q]: C row=quad*4+j -> key, col=l15 -> q
            f32x4 s = __builtin_amdgcn_mfma_f32_16x16x16bf16_1k(kf, qf[tt], (f32x4)0.0f, 0, 0, 0);
            const float p0 = __builtin_amdgcn_exp2f(s[0]);
            const float p1 = __builtin_amdgcn_exp2f(s[1]);
            const float p2 = __builtin_amdgcn_exp2f(s[2]);
            const float p3 = __builtin_amdgcn_exp2f(s[3]);
            lp[tt] += (p0 + p1) + (p2 + p3);
            // P C-layout == K=16 B-frag layout -> PV straight from registers
            acc[tt] = __builtin_amdgcn_mfma_f32_16x16x16bf16_1k(vf, pk4bf(p0, p1, p2, p3), acc[tt], 0, 0, 0);
        }
    }

    // ---- denominators: cross-quad reduce ----
    float linv[4];
    #pragma unroll
    for (int t = 0; t < 4; ++t) {
        float v = lp[t];
        v += __shfl_xor(v, 16, 64);
        v += __shfl_xor(v, 32, 64);
        linv[t] = __builtin_amdgcn_rcpf(v);
    }

    // ---- epilogue: LePE from resident V^T, normalize, f32x4 stores ----
    #pragma unroll
    for (int j = 0; j < 4; ++j) {
        const int d = quad * 4 + j;
        float w9[9];
        #pragma unroll
        for (int o = 0; o < 9; ++o) w9[o] = Wl[d * 9 + o];
        const float bs = Bl[d];
        #pragma unroll
        for (int t = 0; t < 4; ++t) {
            const int q = q0 + t * 16 + l15;
            const int y = q >> 3, x = q & 7;
            float lep = bs;
            #pragma unroll
            for (int dy = 0; dy < 3; ++dy) {
                #pragma unroll
                for (int dx = 0; dx < 3; ++dx) {
                    const int yy = y + dy - 1, xx = x + dx - 1;
                    const bool ok = ((unsigned)yy < 64u) && ((unsigned)xx < 8u);
                    const int tt = (q + (dy - 1) * 8 + (dx - 1)) & 511;   // masked if OOB
                    lep += (ok ? w9[dy * 3 + dx] : 0.0f) * bf2f(Vt[d * VSTR + tt]);
                }
            }
            acc[t][j] = acc[t][j] * linv[t] + lep;
        }
    }
    float* gO = out + base;
    #pragma unroll
    for (int t = 0; t < 4; ++t) {
        const int q = q0 + t * 16 + l15;
        *(f32x4*)(gO + (size_t)(q >> 3) * 4096 + (size_t)(q & 7) * 64 + hc + quad * 4) = acc[t];
    }
}

extern "C" void kernel_launch(void* const* d_in, const int* in_sizes, int n_in,
                              void* d_out, int out_size, void* d_ws, size_t ws_size,
                              hipStream_t stream) {
    const float* qkv   = (const float*)d_in[0];
    const float* wconv = (const float*)d_in[1];
    const float* bconv = (const float*)d_in[2];
    float* outp = (float*)d_out;
    hipLaunchKernelGGL(CSSA_69355131896243_kernel, dim3(1024), dim3(512), 0, stream,
                       qkv, wconv, bconv, outp);
}

// Round 6
// 200.613 us; speedup vs baseline: 2.4910x; 1.3419x over previous
//
#include <hip/hip_runtime.h>
#include <stdint.h>

// CSSA: B=32, H=W=64, C=64, heads=4, hd=16, strip windows 64x8 -> 256 windows.
// Round 6: block=(window,head), 512 thr = 8 waves, wave = 64 queries (4 tiles).
// K (bf16, natural) + V^T (bf16) in LDS (37.8 KB) -> 3 blocks/CU at
// __launch_bounds__(512,6): 24 waves/CU, VGPR budget 85 (no spill — r4/r5's
// forced 8 waves/EU spilled: VGPR=32 + 200-800 MB scratch traffic).
// QK^T computed transposed (A=K,B=Q) so P's C-layout == K=16 B-frag layout:
// PV MFMA consumes P straight from registers, zero cross-lane traffic.
#define KSTR2 20    // K row: 16 ch + 4 pad (40 B)
#define VSTR  520   // Vt row: 512 tok + 8 pad

typedef __attribute__((ext_vector_type(4))) short          short4v;
typedef __attribute__((ext_vector_type(4))) float          f32x4;
typedef __attribute__((ext_vector_type(4))) unsigned short us4;
typedef __bf16 bf2_t __attribute__((ext_vector_type(2)));

__device__ __forceinline__ unsigned short f2bf(float f) {   // round-half-up
    union { float f; unsigned int u; } x; x.f = f;
    return (unsigned short)((x.u + 0x8000u) >> 16);
}
__device__ __forceinline__ float bf2f(unsigned short u) {
    union { unsigned int i; float f; } x; x.i = ((unsigned int)u) << 16; return x.f;
}
__device__ __forceinline__ unsigned int pk2bf(float lo, float hi) {
#if __has_builtin(__builtin_amdgcn_cvt_pk_bf16_f32)
    union { bf2_t v; unsigned int u; } c;
    c.v = __builtin_amdgcn_cvt_pk_bf16_f32(lo, hi);     // 1 VALU op
    return c.u;
#else
    union { float f; unsigned int u; } a, b; a.f = lo; b.f = hi;
    return __builtin_amdgcn_perm(b.u + 0x8000u, a.u + 0x8000u, 0x07060302u);
#endif
}
__device__ __forceinline__ short4v pk4bf(float a, float b, float c, float d) {
    union { short4v s; unsigned int u[2]; } p;
    p.u[0] = pk2bf(a, b);
    p.u[1] = pk2bf(c, d);
    return p.s;
}

__global__ __launch_bounds__(512, 6)
void CSSA_69355131896243_kernel(const float* __restrict__ qkv,
                                const float* __restrict__ wconv,
                                const float* __restrict__ bconv,
                                float* __restrict__ out)
{
    __shared__ unsigned short Kl[512 * KSTR2];   // 20480 B  K[token][d] bf16
    __shared__ unsigned short Vt[16 * VSTR];     // 16640 B  V^T[d][token] bf16
    __shared__ float Wl[144];                    // this head's 16x9 conv weights
    __shared__ float Bl[16];

    const int tid  = threadIdx.x;
    const int wave = tid >> 6, lane = tid & 63, quad = lane >> 4, l15 = lane & 15;

    // bid -> (window, head): head-siblings of a window are 8 apart -> same XCD
    // under round-robin dispatch -> shared Q/K/V/out lines merge in L2.
    const int bid = blockIdx.x;
    const int win = (bid & 7) * 32 + (bid >> 5);
    const int h   = (bid >> 3) & 3;
    const int b   = win >> 3, wx = win & 7;

    const size_t ONE  = (size_t)32 * 4096 * 64;
    const size_t base = ((size_t)b * 4096 + (size_t)wx * 8) * 64;
    const float* gQ = qkv + base;
    const float* gK = qkv + ONE + base;
    const float* gV = qkv + 2 * ONE + base;
    const int hc = h * 16;

    // ---- stage this head's K (natural) + V^T as bf16 ----
    {
        const int c4 = tid & 3;          // 4-ch group within head
        const int t0 = tid >> 2;         // 128 tokens per round
        #pragma unroll
        for (int r = 0; r < 4; ++r) {
            const int t = r * 128 + t0;
            const size_t goff = (size_t)(t >> 3) * 4096 + (size_t)(t & 7) * 64 + hc + c4 * 4;
            f32x4 kd = *(const f32x4*)(gK + goff);
            f32x4 vd = *(const f32x4*)(gV + goff);
            us4 kb;
            #pragma unroll
            for (int j = 0; j < 4; ++j) kb[j] = f2bf(kd[j]);
            *(us4*)(&Kl[t * KSTR2 + c4 * 4]) = kb;
            #pragma unroll
            for (int j = 0; j < 4; ++j) Vt[(c4 * 4 + j) * VSTR + t] = f2bf(vd[j]);
        }
    }
    if (tid < 144) Wl[tid] = wconv[h * 144 + tid];
    if (tid < 16)  Bl[tid] = bconv[hc + tid];

    // ---- Q prefetch + pack (independent of LDS -> overlaps barrier wait) ----
    const float SCL = 0.25f * 1.44269504088896341f;   // scale*log2(e) folded in
    const int q0 = wave * 64;
    short4v qf[4];   // B[k=d=quad*4+i][n=q=l15]
    #pragma unroll
    for (int t = 0; t < 4; ++t) {
        const int q = q0 + t * 16 + l15;
        f32x4 qv = *(const f32x4*)(gQ + (size_t)(q >> 3) * 4096 + (size_t)(q & 7) * 64 + hc + quad * 4);
        qf[t] = pk4bf(qv[0] * SCL, qv[1] * SCL, qv[2] * SCL, qv[3] * SCL);
    }
    __syncthreads();

    f32x4 acc[4];
    float lp[4];
    #pragma unroll
    for (int t = 0; t < 4; ++t) { acc[t] = (f32x4)0.0f; lp[t] = 0.0f; }

    // ---- main loop: 32 chunks x 16 keys, all frags from LDS (imm offsets) ----
    #pragma unroll 4
    for (int c = 0; c < 32; ++c) {
        // K A-frag: A[m=key=l15][k=d=quad*4+i]
        const short4v kf = *(const short4v*)(&Kl[(c * 16 + l15) * KSTR2 + quad * 4]);
        // V A-frag for PV: A[m=d=l15][k=key=quad*4+i]
        const short4v vf = *(const short4v*)(&Vt[l15 * VSTR + c * 16 + quad * 4]);
        #pragma unroll
        for (int t = 0; t < 4; ++t) {
            // s^T[key][q]: C row=quad*4+j -> key, col=l15 -> q
            f32x4 s = __builtin_amdgcn_mfma_f32_16x16x16bf16_1k(kf, qf[t], (f32x4)0.0f, 0, 0, 0);
            const float p0 = __builtin_amdgcn_exp2f(s[0]);
            const float p1 = __builtin_amdgcn_exp2f(s[1]);
            const float p2 = __builtin_amdgcn_exp2f(s[2]);
            const float p3 = __builtin_amdgcn_exp2f(s[3]);
            lp[t] += (p0 + p1) + (p2 + p3);
            // P C-layout == K=16 B-frag layout -> PV straight from registers
            acc[t] = __builtin_amdgcn_mfma_f32_16x16x16bf16_1k(vf, pk4bf(p0, p1, p2, p3), acc[t], 0, 0, 0);
        }
    }

    // ---- denominators: cross-quad reduce ----
    float linv[4];
    #pragma unroll
    for (int t = 0; t < 4; ++t) {
        float v = lp[t];
        v += __shfl_xor(v, 16, 64);
        v += __shfl_xor(v, 32, 64);
        linv[t] = __builtin_amdgcn_rcpf(v);
    }

    // ---- epilogue: LePE from resident V^T, normalize, f32x4 stores ----
    #pragma unroll
    for (int j = 0; j < 4; ++j) {
        const int d = quad * 4 + j;
        float w9[9];
        #pragma unroll
        for (int o = 0; o < 9; ++o) w9[o] = Wl[d * 9 + o];
        const float bs = Bl[d];
        #pragma unroll
        for (int t = 0; t < 4; ++t) {
            const int q = q0 + t * 16 + l15;
            const int y = q >> 3, x = q & 7;
            float lep = bs;
            #pragma unroll
            for (int dy = 0; dy < 3; ++dy) {
                #pragma unroll
                for (int dx = 0; dx < 3; ++dx) {
                    const int yy = y + dy - 1, xx = x + dx - 1;
                    const bool ok = ((unsigned)yy < 64u) && ((unsigned)xx < 8u);
                    const int tt = (q + (dy - 1) * 8 + (dx - 1)) & 511;   // masked if OOB
                    lep += (ok ? w9[dy * 3 + dx] : 0.0f) * bf2f(Vt[d * VSTR + tt]);
                }
            }
            acc[t][j] = acc[t][j] * linv[t] + lep;
        }
    }
    float* gO = out + base;
    #pragma unroll
    for (int t = 0; t < 4; ++t) {
        const int q = q0 + t * 16 + l15;
        *(f32x4*)(gO + (size_t)(q >> 3) * 4096 + (size_t)(q & 7) * 64 + hc + quad * 4) = acc[t];
    }
}

extern "C" void kernel_launch(void* const* d_in, const int* in_sizes, int n_in,
                              void* d_out, int out_size, void* d_ws, size_t ws_size,
                              hipStream_t stream) {
    const float* qkv   = (const float*)d_in[0];
    const float* wconv = (const float*)d_in[1];
    const float* bconv = (const float*)d_in[2];
    float* outp = (float*)d_out;
    hipLaunchKernelGGL(CSSA_69355131896243_kernel, dim3(1024), dim3(512), 0, stream,
                       qkv, wconv, bconv, outp);
}